// Round 6
// baseline (204.167 us; speedup 1.0000x reference)
//
#include <hip/hip_runtime.h>
#include <math.h>

#define N_   8192
#define IN_  512
#define ZD   128
#define CC   64
#define HD   50
#define EPSF 1e-8f

typedef float vf4 __attribute__((ext_vector_type(4)));

__device__ __forceinline__ float softplus_f(float t) {
    return fmaxf(t, 0.f) + log1pf(expf(-fabsf(t)));   // stable softplus
}

// ============================================================================
// k_pre: fused preprocessing (unchanged from round 4/5).
// ============================================================================
__global__ __launch_bounds__(256) void k_pre(const int* __restrict__ c,
                                             const float* __restrict__ W1,
                                             const float* __restrict__ z,
                                             const float* __restrict__ Wz,
                                             const float* __restrict__ bz,
                                             float* __restrict__ W1t,
                                             float* __restrict__ fz,
                                             int* __restrict__ counts,
                                             int* __restrict__ offsets,
                                             int* __restrict__ grouped) {
    int tid = threadIdx.x;
    int b   = blockIdx.x;
    if (b < CC) {
        __shared__ int hist[CC];
        __shared__ int cursor;
        __shared__ int off_s;
        if (tid < CC) hist[tid] = 0;
        if (tid == 0) cursor = 0;
        __syncthreads();
        for (int i = tid; i < N_; i += 256) atomicAdd(&hist[c[i]], 1);
        __syncthreads();
        if (tid == 0) {
            int off = 0;
            for (int q = 0; q < b; ++q) off += hist[q];
            off_s = off;
            counts[b]  = hist[b];
            offsets[b] = off;
        }
        __syncthreads();
        int off = off_s;
        for (int i = tid; i < N_; i += 256) {
            if (c[i] == b) {
                int p = atomicAdd(&cursor, 1);
                grouped[off + p] = i;
            }
        }
    } else if (b < 192) {
        int idx = (b - 64) * 256 + tid;          // 64*512 = 32768
        int d = idx >> 6, k = idx & 63;
        float v = (k < HD) ? W1[d * HD + k] : 0.f;
        W1t[k * IN_ + d] = v;
    } else {
        __shared__ float sz[32 * ZD];            // 16 KB
        int row0 = (b - 192) * 32;
        vf4* s4 = (vf4*)sz;
        const vf4* z4 = (const vf4*)(z + (size_t)row0 * ZD);
        #pragma unroll
        for (int f = 0; f < 4; ++f) s4[tid + f * 256] = z4[tid + f * 256];
        __syncthreads();
        int cp = tid & 31, rg = tid >> 5;
        const vf4* Wz4 = (const vf4*)Wz;
        vf4 bb = ((const vf4*)bz)[cp];
        vf4 acc[4];
        #pragma unroll
        for (int r = 0; r < 4; ++r) acc[r] = bb;
        #pragma unroll 1
        for (int d4 = 0; d4 < 32; ++d4) {
            vf4 w0 = Wz4[(4 * d4 + 0) * 32 + cp];
            vf4 w1 = Wz4[(4 * d4 + 1) * 32 + cp];
            vf4 w2 = Wz4[(4 * d4 + 2) * 32 + cp];
            vf4 w3 = Wz4[(4 * d4 + 3) * 32 + cp];
            #pragma unroll
            for (int r = 0; r < 4; ++r) {
                vf4 a = s4[(rg * 4 + r) * 32 + d4];
                acc[r] += a[0] * w0;
                acc[r] += a[1] * w1;
                acc[r] += a[2] * w2;
                acc[r] += a[3] * w3;
            }
        }
        vf4* fz4 = (vf4*)fz;
        #pragma unroll
        for (int r = 0; r < 4; ++r)
            fz4[(size_t)(row0 + rg * 4 + r) * 32 + cp] = acc[r];
    }
}

// ============================================================================
// k_hfx: unchanged from round 5 (LDS-tiled, padded, conflict-free).
// ============================================================================
#define PAD 17
__global__ __launch_bounds__(256) void k_hfx(const float* __restrict__ x,
                                             const float* __restrict__ W1t,
                                             const float* __restrict__ b1,
                                             const float* __restrict__ W2,
                                             const float* __restrict__ b2,
                                             float* __restrict__ fx) {
    __shared__ float sx[32 * 4 * PAD];
    __shared__ float sw[64 * 4 * PAD];
    __shared__ float sh[32 * 4 * PAD];
    int tid  = threadIdx.x;
    int row0 = blockIdx.x * 32;
    vf4* sx4 = (vf4*)sx;
    vf4* sw4 = (vf4*)sw;
    const vf4* x4g  = (const vf4*)x;
    const vf4* W1t4 = (const vf4*)W1t;

    int cp = tid & 15, rg = tid >> 4;
    float acc0[4] = {0.f, 0.f, 0.f, 0.f};
    float acc1[4] = {0.f, 0.f, 0.f, 0.f};

    #pragma unroll 1
    for (int kc = 0; kc < 8; ++kc) {
        __syncthreads();
        #pragma unroll
        for (int f = 0; f < 2; ++f) {
            int idx = tid + f * 256;
            int row = idx >> 4, q = idx & 15;
            sx4[row * PAD + q] = x4g[(size_t)(row0 + row) * 128 + kc * 16 + q];
        }
        #pragma unroll
        for (int f = 0; f < 4; ++f) {
            int idx = tid + f * 256;
            int k = idx >> 4, q = idx & 15;
            sw4[k * PAD + q] = W1t4[(size_t)k * 128 + kc * 16 + q];
        }
        __syncthreads();
        #pragma unroll 2
        for (int d4 = 0; d4 < 16; ++d4) {
            vf4 a0 = sx4[(2 * rg + 0) * PAD + d4];
            vf4 a1 = sx4[(2 * rg + 1) * PAD + d4];
            #pragma unroll
            for (int i = 0; i < 4; ++i) {
                vf4 w = sw4[(cp + 16 * i) * PAD + d4];
                acc0[i] += a0[0] * w[0] + a0[1] * w[1] + a0[2] * w[2] + a0[3] * w[3];
                acc1[i] += a1[0] * w[0] + a1[1] * w[1] + a1[2] * w[2] + a1[3] * w[3];
            }
        }
    }
    __syncthreads();
    #pragma unroll
    for (int i = 0; i < 4; ++i) {
        int k = cp + 16 * i;
        float bb = (k < HD) ? b1[k] : 0.f;
        sh[(2 * rg + 0) * 4 * PAD + k] = fmaxf(acc0[i] + bb, 0.f);
        sh[(2 * rg + 1) * 4 * PAD + k] = fmaxf(acc1[i] + bb, 0.f);
    }
    __syncthreads();
    {
        int cp2 = tid & 31, rg2 = tid >> 5;
        const vf4* W24 = (const vf4*)W2;
        const vf4* sh4 = (const vf4*)sh;
        vf4 bb = ((const vf4*)b2)[cp2];
        vf4 acc[4];
        #pragma unroll
        for (int r = 0; r < 4; ++r) acc[r] = bb;
        #pragma unroll 1
        for (int d4 = 0; d4 < 12; ++d4) {
            vf4 w0 = W24[(4 * d4 + 0) * 32 + cp2];
            vf4 w1 = W24[(4 * d4 + 1) * 32 + cp2];
            vf4 w2 = W24[(4 * d4 + 2) * 32 + cp2];
            vf4 w3 = W24[(4 * d4 + 3) * 32 + cp2];
            #pragma unroll
            for (int r = 0; r < 4; ++r) {
                vf4 a = sh4[(rg2 * 4 + r) * PAD + d4];
                acc[r] += a[0] * w0;
                acc[r] += a[1] * w1;
                acc[r] += a[2] * w2;
                acc[r] += a[3] * w3;
            }
        }
        #pragma unroll 1
        for (int d = 48; d < HD; ++d) {
            vf4 w = W24[d * 32 + cp2];
            #pragma unroll
            for (int r = 0; r < 4; ++r)
                acc[r] += sh[(rg2 * 4 + r) * 4 * PAD + d] * w;
        }
        vf4* fx4 = (vf4*)fx;
        #pragma unroll
        for (int r = 0; r < 4; ++r)
            fx4[(size_t)(row0 + rg2 * 4 + r) * 32 + cp2] = acc[r];
    }
}

// ============================================================================
// k_u v2: tiled GEMM  u[i-tile] = fx[i-tile] @ Ws[cat].
// Block = (cat, 64-row i-tile). 256 thr: it=tid>>4 (4 rows each), jt=tid&15
// (8 e-cols: jt and jt+16 chunks). fx tile staged with XOR k-swizzle
// (conflict-free strided reads); Ws is k-major already -> natural staging.
// ============================================================================
#define TI_U 6
__global__ __launch_bounds__(256) void k_u(const float* __restrict__ fx,
                                           const float* __restrict__ Ws,
                                           const int* __restrict__ grouped,
                                           const int* __restrict__ offsets,
                                           const int* __restrict__ counts,
                                           float* __restrict__ u) {
    __shared__ float sfx[64 * ZD];               // 32 KB (swizzled k-chunks)
    __shared__ float sws[64 * ZD];               // 32 KB (Ws k-chunk, natural)
    int tid = threadIdx.x;
    int it = tid >> 4, jt = tid & 15;
    int cat = blockIdx.x / TI_U;
    int t   = blockIdx.x % TI_U;
    int off = offsets[cat], cnt = counts[cat];
    int i0 = t * 64;
    if (i0 >= cnt) return;
    int mI = min(64, cnt - i0);

    const vf4* fx4g = (const vf4*)fx;
    const vf4* Ws4  = (const vf4*)(Ws + (size_t)cat * ZD * ZD);
    vf4* sfx4 = (vf4*)sfx;
    vf4* sws4 = (vf4*)sws;

    // stage fx tile: rows 0..63, cols swizzled by (row>>2)&7
    #pragma unroll
    for (int f = 0; f < 8; ++f) {
        int idx = tid + f * 256;                 // 2048 = 64 x 32
        int row = idx >> 5, q = idx & 31;
        int n = (row < mI) ? grouped[off + i0 + row] : -1;
        vf4 v = {0.f, 0.f, 0.f, 0.f};
        if (n >= 0) v = fx4g[(size_t)n * 32 + q];
        sfx4[row * 32 + (q ^ ((row >> 2) & 7))] = v;
    }

    vf4 dot[4][2];
    #pragma unroll
    for (int r = 0; r < 4; ++r) { dot[r][0] = (vf4){0,0,0,0}; dot[r][1] = (vf4){0,0,0,0}; }

    #pragma unroll 1
    for (int kc = 0; kc < 2; ++kc) {             // K-chunks of 64
        __syncthreads();
        #pragma unroll
        for (int f = 0; f < 8; ++f) {            // stage Ws chunk: 64 d x 32 q
            int idx = tid + f * 256;
            int d = idx >> 5, q = idx & 31;
            sws4[d * 32 + q] = Ws4[(size_t)(kc * 64 + d) * 32 + q];
        }
        __syncthreads();
        #pragma unroll 1
        for (int kq = 0; kq < 16; ++kq) {
            int kqg = kc * 16 + kq;              // global k-vf4 index
            vf4 a[4];
            #pragma unroll
            for (int r = 0; r < 4; ++r)
                a[r] = sfx4[(4 * it + r) * 32 + (kqg ^ (it & 7))];
            #pragma unroll
            for (int ek = 0; ek < 4; ++ek) {
                int d = 4 * kq + ek;
                vf4 b0 = sws4[d * 32 + jt];
                vf4 b1 = sws4[d * 32 + jt + 16];
                #pragma unroll
                for (int r = 0; r < 4; ++r) {
                    dot[r][0] += a[r][ek] * b0;
                    dot[r][1] += a[r][ek] * b1;
                }
            }
        }
    }
    vf4* u4 = (vf4*)u;
    #pragma unroll
    for (int r = 0; r < 4; ++r) {
        int row = 4 * it + r;
        if (row < mI) {
            int n = grouped[off + i0 + row];
            u4[(size_t)n * 32 + jt]      = dot[r][0];
            u4[(size_t)n * 32 + jt + 16] = dot[r][1];
        }
    }
}

// ---- logT[n] = log(softplus(dot(u[n], fz[n])) + eps).  1 wave/row ----
__global__ __launch_bounds__(256) void k_T(const float* __restrict__ u,
                                           const float* __restrict__ fz,
                                           float* __restrict__ logT) {
    int lane = threadIdx.x & 63;
    int n = blockIdx.x * 4 + (threadIdx.x >> 6);
    const float2* u2 = (const float2*)(u  + (size_t)n * ZD);
    const float2* f2 = (const float2*)(fz + (size_t)n * ZD);
    float2 a = u2[lane], b = f2[lane];
    float p = a.x * b.x + a.y * b.y;
    #pragma unroll
    for (int s = 32; s >= 1; s >>= 1) p += __shfl_down(p, s, 64);
    if (lane == 0) logT[n] = logf(softplus_f(p) + EPSF);
}

// ============================================================================
// k_neg v3: per-(cat, 64-row i-tile) tiled GEMM over the group's score
// matrix. su = u rows (natural, XOR k-swizzle); sfzT = fz transposed
// [k][j] with XOR chunk swizzle (4-way max on staging writes, free reads).
// Dots live in registers over full K=128; masked softplus into per-thread
// partials; shfl-xor reduce over 16 j-threads; fused final output.
// ============================================================================
#define TI_N 6
__global__ __launch_bounds__(256) void k_neg(const int* __restrict__ grouped,
                                             const int* __restrict__ offsets,
                                             const int* __restrict__ counts,
                                             const float* __restrict__ u,
                                             const float* __restrict__ fz,
                                             const float* __restrict__ logT,
                                             float* __restrict__ out) {
    __shared__ float su[64 * ZD];                // 32 KB
    __shared__ float sfzT[ZD * 64];              // 32 KB, [k][j] swizzled
    int tid = threadIdx.x;
    int it = tid >> 4, jt = tid & 15;
    int cat = blockIdx.x / TI_N;
    int t   = blockIdx.x % TI_N;
    int off = offsets[cat], cnt = counts[cat];
    int i0 = t * 64;
    if (i0 >= cnt) return;
    int mI = min(64, cnt - i0);

    const vf4* u4g  = (const vf4*)u;
    const vf4* fz4g = (const vf4*)fz;
    vf4* su4   = (vf4*)su;
    vf4* sfzT4 = (vf4*)sfzT;

    // stage su tile (rows of this i-tile), swizzled k-chunks
    #pragma unroll
    for (int f = 0; f < 8; ++f) {
        int idx = tid + f * 256;
        int row = idx >> 5, q = idx & 31;
        int n = (row < mI) ? grouped[off + i0 + row] : -1;
        vf4 v = {0.f, 0.f, 0.f, 0.f};
        if (n >= 0) v = u4g[(size_t)n * 32 + q];
        su4[row * 32 + (q ^ ((row >> 2) & 7))] = v;
    }

    float negacc[4] = {0.f, 0.f, 0.f, 0.f};

    #pragma unroll 1
    for (int jb = 0; jb < cnt; jb += 64) {       // j-chunks of 64
        int mJ = min(64, cnt - jb);
        __syncthreads();                         // prior reads done (covers su too)
        // stage fz chunk transposed: element (k, jc) -> row k, chunk (jc>>2)^(q&7)
        #pragma unroll
        for (int f = 0; f < 8; ++f) {
            int idx = tid + f * 256;
            int jc = idx >> 5, q = idx & 31;
            int n = (jc < mJ) ? grouped[off + jb + jc] : -1;
            vf4 v = {0.f, 0.f, 0.f, 0.f};
            if (n >= 0) v = fz4g[(size_t)n * 32 + q];
            int colc = (jc >> 2) ^ (q & 7);
            #pragma unroll
            for (int e = 0; e < 4; ++e)
                sfzT[(4 * q + e) * 64 + 4 * colc + (jc & 3)] = v[e];
        }
        __syncthreads();

        vf4 dot[4];
        #pragma unroll
        for (int r = 0; r < 4; ++r) dot[r] = (vf4){0.f, 0.f, 0.f, 0.f};
        #pragma unroll 1
        for (int kq = 0; kq < 32; ++kq) {
            vf4 a[4];
            #pragma unroll
            for (int r = 0; r < 4; ++r)
                a[r] = su4[(4 * it + r) * 32 + (kq ^ (it & 7))];
            #pragma unroll
            for (int ek = 0; ek < 4; ++ek) {
                int k = 4 * kq + ek;
                vf4 b = sfzT4[k * 16 + (jt ^ (kq & 7))];
                #pragma unroll
                for (int r = 0; r < 4; ++r)
                    dot[r] += a[r][ek] * b;
            }
        }
        #pragma unroll
        for (int r = 0; r < 4; ++r) {
            #pragma unroll
            for (int s = 0; s < 4; ++s) {
                if (4 * jt + s < mJ) negacc[r] += softplus_f(dot[r][s]);
            }
        }
    }

    // reduce over the 16 j-threads (lanes xor 1,2,4,8 stay in 16-group)
    #pragma unroll
    for (int r = 0; r < 4; ++r) {
        float v = negacc[r];
        #pragma unroll
        for (int s = 8; s >= 1; s >>= 1) v += __shfl_xor(v, s, 64);
        negacc[r] = v;
    }
    if (jt == 0) {
        #pragma unroll
        for (int r = 0; r < 4; ++r) {
            int row = 4 * it + r;
            if (row < mI) {
                int n = grouped[off + i0 + row];
                out[n] = logT[n] - logf(negacc[r] / (float)cnt + EPSF);
            }
        }
    }
}

extern "C" void kernel_launch(void* const* d_in, const int* in_sizes, int n_in,
                              void* d_out, int out_size, void* d_ws, size_t ws_size,
                              hipStream_t stream) {
    const float* x  = (const float*)d_in[0];
    const int*   c  = (const int*)  d_in[1];
    const float* z  = (const float*)d_in[2];
    const float* W1 = (const float*)d_in[3];
    const float* b1 = (const float*)d_in[4];
    const float* W2 = (const float*)d_in[5];
    const float* b2 = (const float*)d_in[6];
    const float* Wz = (const float*)d_in[7];
    const float* bz = (const float*)d_in[8];
    const float* Ws = (const float*)d_in[9];
    float* out = (float*)d_out;

    float* ws   = (float*)d_ws;
    float* W1t  = ws;                            // 64*512
    float* fx   = W1t + 64 * IN_;                // N*128
    float* fz   = fx  + (size_t)N_ * ZD;         // N*128
    float* u    = fz  + (size_t)N_ * ZD;         // N*128
    float* logT = u   + (size_t)N_ * ZD;         // N
    int* counts  = (int*)(logT + N_);            // 64
    int* offsets = counts + CC;                  // 64
    int* grouped = offsets + CC;                 // N

    k_pre <<<CC + 128 + N_ / 32, 256, 0, stream>>>(c, W1, z, Wz, bz, W1t, fz,
                                                   counts, offsets, grouped);
    k_hfx <<<N_ / 32, 256, 0, stream>>>(x, W1t, b1, W2, b2, fx);
    k_u   <<<CC * TI_U, 256, 0, stream>>>(fx, Ws, grouped, offsets, counts, u);
    k_T   <<<N_ / 4, 256, 0, stream>>>(u, fz, logT);
    k_neg <<<CC * TI_N, 256, 0, stream>>>(grouped, offsets, counts, u, fz, logT, out);
}

// Round 7
// 165.902 us; speedup vs baseline: 1.2307x; 1.2307x over previous
//
#include <hip/hip_runtime.h>
#include <math.h>

#define N_   8192
#define IN_  512
#define ZD   128
#define CC   64
#define HD   50
#define EPSF 1e-8f

typedef float vf4 __attribute__((ext_vector_type(4)));
typedef __attribute__((ext_vector_type(8))) short bfrag;   // 8 bf16 = 4 VGPR

#define MFMA16(a, b, c) __builtin_amdgcn_mfma_f32_16x16x32_bf16((a), (b), (c), 0, 0, 0)

__device__ __forceinline__ float softplus_f(float t) {
    return fmaxf(t, 0.f) + log1pf(expf(-fabsf(t)));   // stable softplus
}
__device__ __forceinline__ unsigned short bf16_rn(float x) {
    unsigned int u = __float_as_uint(x);
    return (unsigned short)((u + 0x7fff + ((u >> 16) & 1)) >> 16);
}
__device__ __forceinline__ float bf16_f(unsigned short h) {
    return __uint_as_float(((unsigned int)h) << 16);
}

// ============================================================================
// k_pre: fused preprocessing. union LDS (33 KB) across roles.
//   blocks 0..63    : per-category grouping
//   blocks 64..191  : W1 transpose fp32 (pad 50->64)
//   blocks 192..447 : fz = z @ Wz + bz  fp32  + fz_hi bf16 epilogue
//   blocks 448..511 : Ws[cat] -> Wst_hi/lo [e][d] bf16 (transpose + split)
// ============================================================================
__global__ __launch_bounds__(256) void k_pre(const int* __restrict__ c,
                                             const float* __restrict__ W1,
                                             const float* __restrict__ z,
                                             const float* __restrict__ Wz,
                                             const float* __restrict__ bz,
                                             const float* __restrict__ Ws,
                                             float* __restrict__ W1t,
                                             float* __restrict__ fz,
                                             unsigned short* __restrict__ fz_hi,
                                             unsigned short* __restrict__ Wst_hi,
                                             unsigned short* __restrict__ Wst_lo,
                                             int* __restrict__ counts,
                                             int* __restrict__ offsets,
                                             int* __restrict__ grouped) {
    __shared__ float smem[64 * 129];             // 33 KB union
    int tid = threadIdx.x;
    int b   = blockIdx.x;
    if (b < CC) {
        __shared__ int hist[CC];
        __shared__ int cursor;
        __shared__ int off_s;
        if (tid < CC) hist[tid] = 0;
        if (tid == 0) cursor = 0;
        __syncthreads();
        for (int i = tid; i < N_; i += 256) atomicAdd(&hist[c[i]], 1);
        __syncthreads();
        if (tid == 0) {
            int off = 0;
            for (int q = 0; q < b; ++q) off += hist[q];
            off_s = off;
            counts[b]  = hist[b];
            offsets[b] = off;
        }
        __syncthreads();
        int off = off_s;
        for (int i = tid; i < N_; i += 256) {
            if (c[i] == b) {
                int p = atomicAdd(&cursor, 1);
                grouped[off + p] = i;
            }
        }
    } else if (b < 192) {
        int idx = (b - 64) * 256 + tid;          // 64*512
        int d = idx >> 6, k = idx & 63;
        float v = (k < HD) ? W1[d * HD + k] : 0.f;
        W1t[k * IN_ + d] = v;
    } else if (b < 448) {
        float* sz = smem;                        // 32*128 = 4096 floats
        int row0 = (b - 192) * 32;
        vf4* s4 = (vf4*)sz;
        const vf4* z4 = (const vf4*)(z + (size_t)row0 * ZD);
        #pragma unroll
        for (int f = 0; f < 4; ++f) s4[tid + f * 256] = z4[tid + f * 256];
        __syncthreads();
        int cp = tid & 31, rg = tid >> 5;
        const vf4* Wz4 = (const vf4*)Wz;
        vf4 bb = ((const vf4*)bz)[cp];
        vf4 acc[4];
        #pragma unroll
        for (int r = 0; r < 4; ++r) acc[r] = bb;
        #pragma unroll 1
        for (int d4 = 0; d4 < 32; ++d4) {
            vf4 w0 = Wz4[(4 * d4 + 0) * 32 + cp];
            vf4 w1 = Wz4[(4 * d4 + 1) * 32 + cp];
            vf4 w2 = Wz4[(4 * d4 + 2) * 32 + cp];
            vf4 w3 = Wz4[(4 * d4 + 3) * 32 + cp];
            #pragma unroll
            for (int r = 0; r < 4; ++r) {
                vf4 a = s4[(rg * 4 + r) * 32 + d4];
                acc[r] += a[0] * w0;
                acc[r] += a[1] * w1;
                acc[r] += a[2] * w2;
                acc[r] += a[3] * w3;
            }
        }
        vf4* fz4 = (vf4*)fz;
        #pragma unroll
        for (int r = 0; r < 4; ++r) {
            int n = row0 + rg * 4 + r;
            fz4[(size_t)n * 32 + cp] = acc[r];
            ushort4 h;
            h.x = bf16_rn(acc[r][0]); h.y = bf16_rn(acc[r][1]);
            h.z = bf16_rn(acc[r][2]); h.w = bf16_rn(acc[r][3]);
            *(ushort4*)(fz_hi + (size_t)n * ZD + cp * 4) = h;
        }
    } else {
        // Ws transpose + hi/lo split, two half-tiles of 64 rows
        int cat = b - 448;
        const float* Wc = Ws + (size_t)cat * ZD * ZD;
        unsigned short* Whi = Wst_hi + (size_t)cat * ZD * ZD;
        unsigned short* Wlo = Wst_lo + (size_t)cat * ZD * ZD;
        #pragma unroll 1
        for (int half = 0; half < 2; ++half) {
            __syncthreads();
            const vf4* src = (const vf4*)(Wc + (size_t)half * 64 * ZD);
            #pragma unroll
            for (int f = 0; f < 8; ++f) {        // 2048 vf4 = 64 rows x 32
                int idx = tid + f * 256;
                int row = idx >> 5, q = idx & 31;
                vf4 v = src[idx];
                #pragma unroll
                for (int e = 0; e < 4; ++e) smem[row * 129 + q * 4 + e] = v[e];
            }
            __syncthreads();
            #pragma unroll 1
            for (int f = 0; f < 32; ++f) {       // 8192 = 128 e x 64 dd
                int idx = tid + f * 256;
                int e = idx >> 6, dd = idx & 63;
                float v = smem[dd * 129 + e];
                unsigned short h = bf16_rn(v);
                Whi[(size_t)e * ZD + half * 64 + dd] = h;
                Wlo[(size_t)e * ZD + half * 64 + dd] = bf16_rn(v - bf16_f(h));
            }
        }
    }
}

// ============================================================================
// k_hfx: fp32 LDS-tiled (round-5, known good); epilogue writes fx hi/lo bf16.
// ============================================================================
#define PAD 17
__global__ __launch_bounds__(256) void k_hfx(const float* __restrict__ x,
                                             const float* __restrict__ W1t,
                                             const float* __restrict__ b1,
                                             const float* __restrict__ W2,
                                             const float* __restrict__ b2,
                                             unsigned short* __restrict__ fx_hi,
                                             unsigned short* __restrict__ fx_lo) {
    __shared__ float sx[32 * 4 * PAD];
    __shared__ float sw[64 * 4 * PAD];
    __shared__ float sh[32 * 4 * PAD];
    int tid  = threadIdx.x;
    int row0 = blockIdx.x * 32;
    vf4* sx4 = (vf4*)sx;
    vf4* sw4 = (vf4*)sw;
    const vf4* x4g  = (const vf4*)x;
    const vf4* W1t4 = (const vf4*)W1t;

    int cp = tid & 15, rg = tid >> 4;
    float acc0[4] = {0.f, 0.f, 0.f, 0.f};
    float acc1[4] = {0.f, 0.f, 0.f, 0.f};

    #pragma unroll 1
    for (int kc = 0; kc < 8; ++kc) {
        __syncthreads();
        #pragma unroll
        for (int f = 0; f < 2; ++f) {
            int idx = tid + f * 256;
            int row = idx >> 4, q = idx & 15;
            sx4[row * PAD + q] = x4g[(size_t)(row0 + row) * 128 + kc * 16 + q];
        }
        #pragma unroll
        for (int f = 0; f < 4; ++f) {
            int idx = tid + f * 256;
            int k = idx >> 4, q = idx & 15;
            sw4[k * PAD + q] = W1t4[(size_t)k * 128 + kc * 16 + q];
        }
        __syncthreads();
        #pragma unroll 2
        for (int d4 = 0; d4 < 16; ++d4) {
            vf4 a0 = sx4[(2 * rg + 0) * PAD + d4];
            vf4 a1 = sx4[(2 * rg + 1) * PAD + d4];
            #pragma unroll
            for (int i = 0; i < 4; ++i) {
                vf4 w = sw4[(cp + 16 * i) * PAD + d4];
                acc0[i] += a0[0] * w[0] + a0[1] * w[1] + a0[2] * w[2] + a0[3] * w[3];
                acc1[i] += a1[0] * w[0] + a1[1] * w[1] + a1[2] * w[2] + a1[3] * w[3];
            }
        }
    }
    __syncthreads();
    #pragma unroll
    for (int i = 0; i < 4; ++i) {
        int k = cp + 16 * i;
        float bb = (k < HD) ? b1[k] : 0.f;
        sh[(2 * rg + 0) * 4 * PAD + k] = fmaxf(acc0[i] + bb, 0.f);
        sh[(2 * rg + 1) * 4 * PAD + k] = fmaxf(acc1[i] + bb, 0.f);
    }
    __syncthreads();
    {
        int cp2 = tid & 31, rg2 = tid >> 5;
        const vf4* W24 = (const vf4*)W2;
        const vf4* sh4 = (const vf4*)sh;
        vf4 bb = ((const vf4*)b2)[cp2];
        vf4 acc[4];
        #pragma unroll
        for (int r = 0; r < 4; ++r) acc[r] = bb;
        #pragma unroll 1
        for (int d4 = 0; d4 < 12; ++d4) {
            vf4 w0 = W24[(4 * d4 + 0) * 32 + cp2];
            vf4 w1 = W24[(4 * d4 + 1) * 32 + cp2];
            vf4 w2 = W24[(4 * d4 + 2) * 32 + cp2];
            vf4 w3 = W24[(4 * d4 + 3) * 32 + cp2];
            #pragma unroll
            for (int r = 0; r < 4; ++r) {
                vf4 a = sh4[(rg2 * 4 + r) * PAD + d4];
                acc[r] += a[0] * w0;
                acc[r] += a[1] * w1;
                acc[r] += a[2] * w2;
                acc[r] += a[3] * w3;
            }
        }
        #pragma unroll 1
        for (int d = 48; d < HD; ++d) {
            vf4 w = W24[d * 32 + cp2];
            #pragma unroll
            for (int r = 0; r < 4; ++r)
                acc[r] += sh[(rg2 * 4 + r) * 4 * PAD + d] * w;
        }
        #pragma unroll
        for (int r = 0; r < 4; ++r) {
            size_t n = (size_t)(row0 + rg2 * 4 + r);
            ushort4 h, l;
            #pragma unroll
            for (int e = 0; e < 4; ++e) {
                unsigned short hh = bf16_rn(acc[r][e]);
                ((unsigned short*)&h)[e] = hh;
                ((unsigned short*)&l)[e] = bf16_rn(acc[r][e] - bf16_f(hh));
            }
            *(ushort4*)(fx_hi + n * ZD + cp2 * 4) = h;
            *(ushort4*)(fx_lo + n * ZD + cp2 * 4) = l;
        }
    }
}

// ============================================================================
// k_u (MFMA): u[i-tile] = fx @ Ws[cat], bf16 hi/lo x3 passes (~fp32 accuracy).
// Block = (cat, 64-i-tile), 4 waves x 16 rows. A-frags per-lane from global
// (held in regs); Wst hi/lo staged in LDS (+8 bf16 row pad -> 2-way max).
// ============================================================================
#define TI_U 6
__global__ __launch_bounds__(256) void k_u(const unsigned short* __restrict__ fx_hi,
                                           const unsigned short* __restrict__ fx_lo,
                                           const unsigned short* __restrict__ Wst_hi,
                                           const unsigned short* __restrict__ Wst_lo,
                                           const int* __restrict__ grouped,
                                           const int* __restrict__ offsets,
                                           const int* __restrict__ counts,
                                           float* __restrict__ u,
                                           unsigned short* __restrict__ u_hi) {
    __shared__ uint4 sWhi[128 * 17];             // 34.8 KB
    __shared__ uint4 sWlo[128 * 17];             // 34.8 KB
    int tid = threadIdx.x;
    int cat = blockIdx.x / TI_U;
    int t   = blockIdx.x % TI_U;
    int off = offsets[cat], cnt = counts[cat];
    int i0 = t * 64;
    if (i0 >= cnt) return;
    int mI = min(64, cnt - i0);

    int lane = tid & 63, wave = tid >> 6;
    int m = lane & 15, quad = lane >> 4;

    // stage Wst hi/lo (2048 uint4 each)
    const uint4* gh = (const uint4*)(Wst_hi + (size_t)cat * ZD * ZD);
    const uint4* gl = (const uint4*)(Wst_lo + (size_t)cat * ZD * ZD);
    #pragma unroll
    for (int f = 0; f < 8; ++f) {
        int idx = tid + f * 256;
        int e = idx >> 4, q = idx & 15;
        sWhi[e * 17 + q] = gh[idx];
        sWlo[e * 17 + q] = gl[idx];
    }

    // A-frags in registers (per-lane global gather)
    int irow = wave * 16 + m;
    int n_g = grouped[off + i0 + min(irow, mI - 1)];
    const unsigned short* fhp = fx_hi + (size_t)n_g * ZD + quad * 8;
    const unsigned short* flp = fx_lo + (size_t)n_g * ZD + quad * 8;
    bfrag a_hi[4], a_lo[4];
    #pragma unroll
    for (int kb = 0; kb < 4; ++kb) {
        a_hi[kb] = *(const bfrag*)(fhp + kb * 32);
        a_lo[kb] = *(const bfrag*)(flp + kb * 32);
    }
    __syncthreads();

    #pragma unroll 1
    for (int et = 0; et < 8; ++et) {             // 8 e-tiles of 16
        vf4 acc = {0.f, 0.f, 0.f, 0.f};
        #pragma unroll
        for (int kb = 0; kb < 4; ++kb) {
            bfrag bh = *(const bfrag*)&sWhi[(et * 16 + m) * 17 + kb * 4 + quad];
            bfrag bl = *(const bfrag*)&sWlo[(et * 16 + m) * 17 + kb * 4 + quad];
            acc = MFMA16(a_hi[kb], bh, acc);
            acc = MFMA16(a_hi[kb], bl, acc);
            acc = MFMA16(a_lo[kb], bh, acc);
        }
        // C layout: col=lane&15 (e-offset), row=quad*4+reg (i-offset)
        #pragma unroll
        for (int r = 0; r < 4; ++r) {
            int ir = wave * 16 + quad * 4 + r;
            if (ir < mI) {
                int n2 = grouped[off + i0 + ir];
                float v = acc[r];
                u[(size_t)n2 * ZD + et * 16 + m] = v;
                u_hi[(size_t)n2 * ZD + et * 16 + m] = bf16_rn(v);
            }
        }
    }
}

// ---- logT[n] = log(softplus(dot(u[n], fz[n])) + eps), fp32.  1 wave/row ----
__global__ __launch_bounds__(256) void k_T(const float* __restrict__ u,
                                           const float* __restrict__ fz,
                                           float* __restrict__ logT) {
    int lane = threadIdx.x & 63;
    int n = blockIdx.x * 4 + (threadIdx.x >> 6);
    const float2* u2 = (const float2*)(u  + (size_t)n * ZD);
    const float2* f2 = (const float2*)(fz + (size_t)n * ZD);
    float2 a = u2[lane], b = f2[lane];
    float p = a.x * b.x + a.y * b.y;
    #pragma unroll
    for (int s = 32; s >= 1; s >>= 1) p += __shfl_down(p, s, 64);
    if (lane == 0) logT[n] = logf(softplus_f(p) + EPSF);
}

// ============================================================================
// k_neg (MFMA): S-tile = u_hi @ fz_hi^T per (cat, 64-i-tile), plain bf16
// (errors average out over the j-mean). A-frags in regs; fz rows staged in
// LDS per 64-j chunk. Row-sums via shfl-xor within 16-lane groups; fused out.
// ============================================================================
#define TI_N 6
__global__ __launch_bounds__(256) void k_neg(const int* __restrict__ grouped,
                                             const int* __restrict__ offsets,
                                             const int* __restrict__ counts,
                                             const unsigned short* __restrict__ u_hi,
                                             const unsigned short* __restrict__ fz_hi,
                                             const float* __restrict__ logT,
                                             float* __restrict__ out) {
    __shared__ uint4 sB[64 * 17];                // 17.4 KB
    int tid = threadIdx.x;
    int cat = blockIdx.x / TI_N;
    int t   = blockIdx.x % TI_N;
    int off = offsets[cat], cnt = counts[cat];
    int i0 = t * 64;
    if (i0 >= cnt) return;
    int mI = min(64, cnt - i0);

    int lane = tid & 63, wave = tid >> 6;
    int m = lane & 15, quad = lane >> 4;

    // A-frags (u_hi rows) in registers
    int irow = wave * 16 + m;
    int n_g = grouped[off + i0 + min(irow, mI - 1)];
    const unsigned short* up = u_hi + (size_t)n_g * ZD + quad * 8;
    bfrag a[4];
    #pragma unroll
    for (int kb = 0; kb < 4; ++kb) a[kb] = *(const bfrag*)(up + kb * 32);

    float negsum[4] = {0.f, 0.f, 0.f, 0.f};

    #pragma unroll 1
    for (int jb = 0; jb < cnt; jb += 64) {
        int mJ = min(64, cnt - jb);
        __syncthreads();
        #pragma unroll
        for (int f = 0; f < 4; ++f) {            // 1024 uint4 = 64 rows x 16
            int idx = tid + f * 256;
            int jr = idx >> 4, q = idx & 15;
            uint4 v = {0u, 0u, 0u, 0u};
            if (jr < mJ) {
                int j_g = grouped[off + jb + jr];
                v = *(const uint4*)(fz_hi + (size_t)j_g * ZD + q * 8);
            }
            sB[jr * 17 + q] = v;
        }
        __syncthreads();
        #pragma unroll 1
        for (int jt = 0; jt < 4; ++jt) {
            vf4 acc = {0.f, 0.f, 0.f, 0.f};
            #pragma unroll
            for (int kb = 0; kb < 4; ++kb) {
                bfrag b = *(const bfrag*)&sB[(jt * 16 + m) * 17 + kb * 4 + quad];
                acc = MFMA16(a[kb], b, acc);
            }
            bool jok = (jt * 16 + m) < mJ;       // col = lane&15
            #pragma unroll
            for (int r = 0; r < 4; ++r)
                if (jok) negsum[r] += softplus_f(acc[r]);
        }
    }

    // reduce cols across the 16 lanes of each quad
    #pragma unroll
    for (int r = 0; r < 4; ++r) {
        float v = negsum[r];
        #pragma unroll
        for (int s = 8; s >= 1; s >>= 1) v += __shfl_xor(v, s, 64);
        negsum[r] = v;
    }
    if (m == 0) {
        #pragma unroll
        for (int r = 0; r < 4; ++r) {
            int ir = wave * 16 + quad * 4 + r;
            if (ir < mI) {
                int n2 = grouped[off + i0 + ir];
                out[n2] = logT[n2] - logf(negsum[r] / (float)cnt + EPSF);
            }
        }
    }
}

extern "C" void kernel_launch(void* const* d_in, const int* in_sizes, int n_in,
                              void* d_out, int out_size, void* d_ws, size_t ws_size,
                              hipStream_t stream) {
    const float* x  = (const float*)d_in[0];
    const int*   c  = (const int*)  d_in[1];
    const float* z  = (const float*)d_in[2];
    const float* W1 = (const float*)d_in[3];
    const float* b1 = (const float*)d_in[4];
    const float* W2 = (const float*)d_in[5];
    const float* b2 = (const float*)d_in[6];
    const float* Wz = (const float*)d_in[7];
    const float* bz = (const float*)d_in[8];
    const float* Ws = (const float*)d_in[9];
    float* out = (float*)d_out;

    float* ws = (float*)d_ws;
    float* W1t  = ws;                                  // 32768 f
    float* fz   = W1t + 64 * IN_;                      // N*128 f
    float* u    = fz  + (size_t)N_ * ZD;               // N*128 f
    float* logT = u   + (size_t)N_ * ZD;               // N f
    unsigned short* fx_hi  = (unsigned short*)(logT + N_);               // N*128 bf16
    unsigned short* fx_lo  = fx_hi + (size_t)N_ * ZD;
    unsigned short* fz_hi  = fx_lo + (size_t)N_ * ZD;
    unsigned short* u_hi   = fz_hi + (size_t)N_ * ZD;
    unsigned short* Wst_hi = u_hi  + (size_t)N_ * ZD;                    // CC*128*128
    unsigned short* Wst_lo = Wst_hi + (size_t)CC * ZD * ZD;
    int* counts  = (int*)(Wst_lo + (size_t)CC * ZD * ZD);
    int* offsets = counts + CC;
    int* grouped = offsets + CC;

    k_pre <<<512, 256, 0, stream>>>(c, W1, z, Wz, bz, Ws, W1t, fz, fz_hi,
                                    Wst_hi, Wst_lo, counts, offsets, grouped);
    k_hfx <<<N_ / 32, 256, 0, stream>>>(x, W1t, b1, W2, b2, fx_hi, fx_lo);
    k_u   <<<CC * TI_U, 256, 0, stream>>>(fx_hi, fx_lo, Wst_hi, Wst_lo,
                                          grouped, offsets, counts, u, u_hi);
    k_T   <<<N_ / 4, 256, 0, stream>>>(u, fz, logT);
    k_neg <<<CC * TI_N, 256, 0, stream>>>(grouped, offsets, counts, u_hi,
                                          fz_hi, logT, out);
}

// Round 8
// 157.951 us; speedup vs baseline: 1.2926x; 1.0503x over previous
//
#include <hip/hip_runtime.h>
#include <math.h>

#define N_   8192
#define IN_  512
#define ZD   128
#define CC   64
#define HD   50
#define EPSF 1e-8f

typedef float vf4 __attribute__((ext_vector_type(4)));
typedef __attribute__((ext_vector_type(8))) short bfrag;   // 8 bf16 = 4 VGPR

#define MFMA16(a, b, c) __builtin_amdgcn_mfma_f32_16x16x32_bf16((a), (b), (c), 0, 0, 0)

__device__ __forceinline__ float softplus_f(float t) {
    return fmaxf(t, 0.f) + log1pf(expf(-fabsf(t)));   // stable softplus
}
__device__ __forceinline__ unsigned short bf16_rn(float x) {
    unsigned int u = __float_as_uint(x);
    return (unsigned short)((u + 0x7fff + ((u >> 16) & 1)) >> 16);
}
__device__ __forceinline__ float bf16_f(unsigned short h) {
    return __uint_as_float(((unsigned int)h) << 16);
}

// ============================================================================
// k_pre: fused preprocessing (unchanged from round 7).
//   blocks 0..63    : per-category grouping
//   blocks 64..191  : W1 transpose fp32 (pad 50->64)
//   blocks 192..447 : fz = z @ Wz + bz  fp32  + fz_hi bf16 epilogue
//   blocks 448..511 : Ws[cat] -> Wst_hi/lo [e][d] bf16 (transpose + split)
// ============================================================================
__global__ __launch_bounds__(256) void k_pre(const int* __restrict__ c,
                                             const float* __restrict__ W1,
                                             const float* __restrict__ z,
                                             const float* __restrict__ Wz,
                                             const float* __restrict__ bz,
                                             const float* __restrict__ Ws,
                                             float* __restrict__ W1t,
                                             float* __restrict__ fz,
                                             unsigned short* __restrict__ fz_hi,
                                             unsigned short* __restrict__ Wst_hi,
                                             unsigned short* __restrict__ Wst_lo,
                                             int* __restrict__ counts,
                                             int* __restrict__ offsets,
                                             int* __restrict__ grouped) {
    __shared__ float smem[64 * 129];             // 33 KB union
    int tid = threadIdx.x;
    int b   = blockIdx.x;
    if (b < CC) {
        __shared__ int hist[CC];
        __shared__ int cursor;
        __shared__ int off_s;
        if (tid < CC) hist[tid] = 0;
        if (tid == 0) cursor = 0;
        __syncthreads();
        for (int i = tid; i < N_; i += 256) atomicAdd(&hist[c[i]], 1);
        __syncthreads();
        if (tid == 0) {
            int off = 0;
            for (int q = 0; q < b; ++q) off += hist[q];
            off_s = off;
            counts[b]  = hist[b];
            offsets[b] = off;
        }
        __syncthreads();
        int off = off_s;
        for (int i = tid; i < N_; i += 256) {
            if (c[i] == b) {
                int p = atomicAdd(&cursor, 1);
                grouped[off + p] = i;
            }
        }
    } else if (b < 192) {
        int idx = (b - 64) * 256 + tid;          // 64*512
        int d = idx >> 6, k = idx & 63;
        float v = (k < HD) ? W1[d * HD + k] : 0.f;
        W1t[k * IN_ + d] = v;
    } else if (b < 448) {
        float* sz = smem;                        // 32*128 floats
        int row0 = (b - 192) * 32;
        vf4* s4 = (vf4*)sz;
        const vf4* z4 = (const vf4*)(z + (size_t)row0 * ZD);
        #pragma unroll
        for (int f = 0; f < 4; ++f) s4[tid + f * 256] = z4[tid + f * 256];
        __syncthreads();
        int cp = tid & 31, rg = tid >> 5;
        const vf4* Wz4 = (const vf4*)Wz;
        vf4 bb = ((const vf4*)bz)[cp];
        vf4 acc[4];
        #pragma unroll
        for (int r = 0; r < 4; ++r) acc[r] = bb;
        #pragma unroll 1
        for (int d4 = 0; d4 < 32; ++d4) {
            vf4 w0 = Wz4[(4 * d4 + 0) * 32 + cp];
            vf4 w1 = Wz4[(4 * d4 + 1) * 32 + cp];
            vf4 w2 = Wz4[(4 * d4 + 2) * 32 + cp];
            vf4 w3 = Wz4[(4 * d4 + 3) * 32 + cp];
            #pragma unroll
            for (int r = 0; r < 4; ++r) {
                vf4 a = s4[(rg * 4 + r) * 32 + d4];
                acc[r] += a[0] * w0;
                acc[r] += a[1] * w1;
                acc[r] += a[2] * w2;
                acc[r] += a[3] * w3;
            }
        }
        vf4* fz4 = (vf4*)fz;
        #pragma unroll
        for (int r = 0; r < 4; ++r) {
            int n = row0 + rg * 4 + r;
            fz4[(size_t)n * 32 + cp] = acc[r];
            ushort4 h;
            h.x = bf16_rn(acc[r][0]); h.y = bf16_rn(acc[r][1]);
            h.z = bf16_rn(acc[r][2]); h.w = bf16_rn(acc[r][3]);
            *(ushort4*)(fz_hi + (size_t)n * ZD + cp * 4) = h;
        }
    } else {
        int cat = b - 448;
        const float* Wc = Ws + (size_t)cat * ZD * ZD;
        unsigned short* Whi = Wst_hi + (size_t)cat * ZD * ZD;
        unsigned short* Wlo = Wst_lo + (size_t)cat * ZD * ZD;
        #pragma unroll 1
        for (int half = 0; half < 2; ++half) {
            __syncthreads();
            const vf4* src = (const vf4*)(Wc + (size_t)half * 64 * ZD);
            #pragma unroll
            for (int f = 0; f < 8; ++f) {        // 2048 vf4 = 64 rows x 32
                int idx = tid + f * 256;
                int row = idx >> 5, q = idx & 31;
                vf4 v = src[idx];
                #pragma unroll
                for (int e = 0; e < 4; ++e) smem[row * 129 + q * 4 + e] = v[e];
            }
            __syncthreads();
            #pragma unroll 1
            for (int f = 0; f < 32; ++f) {       // 8192 = 128 e x 64 dd
                int idx = tid + f * 256;
                int e = idx >> 6, dd = idx & 63;
                float v = smem[dd * 129 + e];
                unsigned short h = bf16_rn(v);
                Whi[(size_t)e * ZD + half * 64 + dd] = h;
                Wlo[(size_t)e * ZD + half * 64 + dd] = bf16_rn(v - bf16_f(h));
            }
        }
    }
}

// ============================================================================
// k_hfx: fp32 LDS-tiled (round-5 proven); epilogue writes fx hi/lo bf16.
// ============================================================================
#define PAD 17
__global__ __launch_bounds__(256) void k_hfx(const float* __restrict__ x,
                                             const float* __restrict__ W1t,
                                             const float* __restrict__ b1,
                                             const float* __restrict__ W2,
                                             const float* __restrict__ b2,
                                             unsigned short* __restrict__ fx_hi,
                                             unsigned short* __restrict__ fx_lo) {
    __shared__ float sx[32 * 4 * PAD];
    __shared__ float sw[64 * 4 * PAD];
    __shared__ float sh[32 * 4 * PAD];
    int tid  = threadIdx.x;
    int row0 = blockIdx.x * 32;
    vf4* sx4 = (vf4*)sx;
    vf4* sw4 = (vf4*)sw;
    const vf4* x4g  = (const vf4*)x;
    const vf4* W1t4 = (const vf4*)W1t;

    int cp = tid & 15, rg = tid >> 4;
    float acc0[4] = {0.f, 0.f, 0.f, 0.f};
    float acc1[4] = {0.f, 0.f, 0.f, 0.f};

    #pragma unroll 1
    for (int kc = 0; kc < 8; ++kc) {
        __syncthreads();
        #pragma unroll
        for (int f = 0; f < 2; ++f) {
            int idx = tid + f * 256;
            int row = idx >> 4, q = idx & 15;
            sx4[row * PAD + q] = x4g[(size_t)(row0 + row) * 128 + kc * 16 + q];
        }
        #pragma unroll
        for (int f = 0; f < 4; ++f) {
            int idx = tid + f * 256;
            int k = idx >> 4, q = idx & 15;
            sw4[k * PAD + q] = W1t4[(size_t)k * 128 + kc * 16 + q];
        }
        __syncthreads();
        #pragma unroll 2
        for (int d4 = 0; d4 < 16; ++d4) {
            vf4 a0 = sx4[(2 * rg + 0) * PAD + d4];
            vf4 a1 = sx4[(2 * rg + 1) * PAD + d4];
            #pragma unroll
            for (int i = 0; i < 4; ++i) {
                vf4 w = sw4[(cp + 16 * i) * PAD + d4];
                acc0[i] += a0[0] * w[0] + a0[1] * w[1] + a0[2] * w[2] + a0[3] * w[3];
                acc1[i] += a1[0] * w[0] + a1[1] * w[1] + a1[2] * w[2] + a1[3] * w[3];
            }
        }
    }
    __syncthreads();
    #pragma unroll
    for (int i = 0; i < 4; ++i) {
        int k = cp + 16 * i;
        float bb = (k < HD) ? b1[k] : 0.f;
        sh[(2 * rg + 0) * 4 * PAD + k] = fmaxf(acc0[i] + bb, 0.f);
        sh[(2 * rg + 1) * 4 * PAD + k] = fmaxf(acc1[i] + bb, 0.f);
    }
    __syncthreads();
    {
        int cp2 = tid & 31, rg2 = tid >> 5;
        const vf4* W24 = (const vf4*)W2;
        const vf4* sh4 = (const vf4*)sh;
        vf4 bb = ((const vf4*)b2)[cp2];
        vf4 acc[4];
        #pragma unroll
        for (int r = 0; r < 4; ++r) acc[r] = bb;
        #pragma unroll 1
        for (int d4 = 0; d4 < 12; ++d4) {
            vf4 w0 = W24[(4 * d4 + 0) * 32 + cp2];
            vf4 w1 = W24[(4 * d4 + 1) * 32 + cp2];
            vf4 w2 = W24[(4 * d4 + 2) * 32 + cp2];
            vf4 w3 = W24[(4 * d4 + 3) * 32 + cp2];
            #pragma unroll
            for (int r = 0; r < 4; ++r) {
                vf4 a = sh4[(rg2 * 4 + r) * PAD + d4];
                acc[r] += a[0] * w0;
                acc[r] += a[1] * w1;
                acc[r] += a[2] * w2;
                acc[r] += a[3] * w3;
            }
        }
        #pragma unroll 1
        for (int d = 48; d < HD; ++d) {
            vf4 w = W24[d * 32 + cp2];
            #pragma unroll
            for (int r = 0; r < 4; ++r)
                acc[r] += sh[(rg2 * 4 + r) * 4 * PAD + d] * w;
        }
        #pragma unroll
        for (int r = 0; r < 4; ++r) {
            size_t n = (size_t)(row0 + rg2 * 4 + r);
            ushort4 h, l;
            #pragma unroll
            for (int e = 0; e < 4; ++e) {
                unsigned short hh = bf16_rn(acc[r][e]);
                ((unsigned short*)&h)[e] = hh;
                ((unsigned short*)&l)[e] = bf16_rn(acc[r][e] - bf16_f(hh));
            }
            *(ushort4*)(fx_hi + n * ZD + cp2 * 4) = h;
            *(ushort4*)(fx_lo + n * ZD + cp2 * 4) = l;
        }
    }
}

// ============================================================================
// k_fused: per (cat, 64-row i-tile):
//   phase U: u-tile = fx @ Ws[cat] (bf16 hi/lo x3 MFMA, r7-proven layout),
//            accumulators stay in registers
//   phase T: logT for own rows = log(softplus(sum_e u*fz)+eps), fp32, via
//            in-register dot + shfl-reduce over the 16 m-lanes
//   phase S: u_hi -> LDS (reuses sWhi region); neg-GEMM vs fz_hi j-chunks
//            (reuses sWlo region); fused final out.
// u / u_hi / logT never touch global memory.
// ============================================================================
#define TI 4
__global__ __launch_bounds__(256) void k_fused(const unsigned short* __restrict__ fx_hi,
                                               const unsigned short* __restrict__ fx_lo,
                                               const unsigned short* __restrict__ Wst_hi,
                                               const unsigned short* __restrict__ Wst_lo,
                                               const float* __restrict__ fz,
                                               const unsigned short* __restrict__ fz_hi,
                                               const int* __restrict__ grouped,
                                               const int* __restrict__ offsets,
                                               const int* __restrict__ counts,
                                               float* __restrict__ out) {
    __shared__ uint4 sWhi[128 * 17];             // 34.8 KB; reused as su (bf16 u-tile)
    __shared__ uint4 sWlo[128 * 17];             // 34.8 KB; reused as sB (fz_hi chunk)
    int tid = threadIdx.x;
    int cat = blockIdx.x >> 2;
    int t   = blockIdx.x & (TI - 1);
    int off = offsets[cat], cnt = counts[cat];
    int i0 = t * 64;
    if (i0 >= cnt) return;
    int mI = min(64, cnt - i0);

    int lane = tid & 63, wave = tid >> 6;
    int m = lane & 15, quad = lane >> 4;

    // ---- stage Wst hi/lo ----
    const uint4* gh = (const uint4*)(Wst_hi + (size_t)cat * ZD * ZD);
    const uint4* gl = (const uint4*)(Wst_lo + (size_t)cat * ZD * ZD);
    #pragma unroll
    for (int f = 0; f < 8; ++f) {
        int idx = tid + f * 256;
        int e = idx >> 4, q = idx & 15;
        sWhi[e * 17 + q] = gh[idx];
        sWlo[e * 17 + q] = gl[idx];
    }

    // ---- A-frags (fx rows) in registers ----
    int irow = wave * 16 + m;
    int n_gA = grouped[off + i0 + min(irow, mI - 1)];
    const unsigned short* fhp = fx_hi + (size_t)n_gA * ZD + quad * 8;
    const unsigned short* flp = fx_lo + (size_t)n_gA * ZD + quad * 8;
    bfrag a_hi[4], a_lo[4];
    #pragma unroll
    for (int kb = 0; kb < 4; ++kb) {
        a_hi[kb] = *(const bfrag*)(fhp + kb * 32);
        a_lo[kb] = *(const bfrag*)(flp + kb * 32);
    }
    __syncthreads();

    // ---- phase U: 8 e-tiles, 3-pass hi/lo MFMA; accumulators in regs ----
    vf4 uacc[8];
    #pragma unroll 1
    for (int et = 0; et < 8; ++et) {
        vf4 acc = {0.f, 0.f, 0.f, 0.f};
        #pragma unroll
        for (int kb = 0; kb < 4; ++kb) {
            bfrag bh = *(const bfrag*)&sWhi[(et * 16 + m) * 17 + kb * 4 + quad];
            bfrag bl = *(const bfrag*)&sWlo[(et * 16 + m) * 17 + kb * 4 + quad];
            acc = MFMA16(a_hi[kb], bh, acc);
            acc = MFMA16(a_hi[kb], bl, acc);
            acc = MFMA16(a_lo[kb], bh, acc);
        }
        uacc[et] = acc;
    }

    // ---- phase T: logT partial dots (fp32), rows ir = wave*16+quad*4+r ----
    int nrow[4];
    float p[4] = {0.f, 0.f, 0.f, 0.f};
    #pragma unroll
    for (int r = 0; r < 4; ++r) {
        int ir = wave * 16 + quad * 4 + r;
        nrow[r] = (ir < mI) ? grouped[off + i0 + ir] : -1;
    }
    #pragma unroll 1
    for (int et = 0; et < 8; ++et) {
        #pragma unroll
        for (int r = 0; r < 4; ++r) {
            if (nrow[r] >= 0)
                p[r] += uacc[et][r] * fz[(size_t)nrow[r] * ZD + et * 16 + m];
        }
    }
    #pragma unroll
    for (int r = 0; r < 4; ++r) {
        float v = p[r];
        #pragma unroll
        for (int s = 8; s >= 1; s >>= 1) v += __shfl_xor(v, s, 64);
        p[r] = v;                                // sum over the 16 m-lanes
    }
    float logT_r[4];
    #pragma unroll
    for (int r = 0; r < 4; ++r) logT_r[r] = logf(softplus_f(p[r]) + EPSF);

    // ---- u_hi tile -> LDS (reuse sWhi region) ----
    __syncthreads();                             // all sWhi/sWlo reads done
    unsigned short* su = (unsigned short*)sWhi;  // [row][e], row stride 136
    #pragma unroll
    for (int et = 0; et < 8; ++et) {
        #pragma unroll
        for (int r = 0; r < 4; ++r) {
            int row = wave * 16 + quad * 4 + r;  // clamped rows hold dup data
            su[row * 136 + et * 16 + m] = bf16_rn(uacc[et][r]);
        }
    }
    __syncthreads();                             // su visible

    // ---- neg A-frags from su: lane m -> i-row wave*16+m ----
    bfrag na[4];
    #pragma unroll
    for (int kb = 0; kb < 4; ++kb)
        na[kb] = *(const bfrag*)&su[(wave * 16 + m) * 136 + kb * 32 + quad * 8];

    uint4* sB = (uint4*)sWlo;
    float negsum[4] = {0.f, 0.f, 0.f, 0.f};

    #pragma unroll 1
    for (int jb = 0; jb < cnt; jb += 64) {
        int mJ = min(64, cnt - jb);
        __syncthreads();                         // prior sB reads done
        #pragma unroll
        for (int f = 0; f < 4; ++f) {            // 1024 uint4 = 64 rows x 16
            int idx = tid + f * 256;
            int jr = idx >> 4, q = idx & 15;
            uint4 v = {0u, 0u, 0u, 0u};
            if (jr < mJ) {
                int j_g = grouped[off + jb + jr];
                v = *(const uint4*)(fz_hi + (size_t)j_g * ZD + q * 8);
            }
            sB[jr * 17 + q] = v;
        }
        __syncthreads();
        #pragma unroll 1
        for (int jt = 0; jt < 4; ++jt) {
            vf4 acc = {0.f, 0.f, 0.f, 0.f};
            #pragma unroll
            for (int kb = 0; kb < 4; ++kb) {
                bfrag b = *(const bfrag*)&sB[(jt * 16 + m) * 17 + kb * 4 + quad];
                acc = MFMA16(na[kb], b, acc);
            }
            bool jok = (jt * 16 + m) < mJ;       // col = lane&15 -> j
            #pragma unroll
            for (int r = 0; r < 4; ++r)
                if (jok) negsum[r] += softplus_f(acc[r]);
        }
    }

    #pragma unroll
    for (int r = 0; r < 4; ++r) {
        float v = negsum[r];
        #pragma unroll
        for (int s = 8; s >= 1; s >>= 1) v += __shfl_xor(v, s, 64);
        negsum[r] = v;
    }
    if (m == 0) {
        #pragma unroll
        for (int r = 0; r < 4; ++r) {
            if (nrow[r] >= 0)
                out[nrow[r]] = logT_r[r] - logf(negsum[r] / (float)cnt + EPSF);
        }
    }
}

extern "C" void kernel_launch(void* const* d_in, const int* in_sizes, int n_in,
                              void* d_out, int out_size, void* d_ws, size_t ws_size,
                              hipStream_t stream) {
    const float* x  = (const float*)d_in[0];
    const int*   c  = (const int*)  d_in[1];
    const float* z  = (const float*)d_in[2];
    const float* W1 = (const float*)d_in[3];
    const float* b1 = (const float*)d_in[4];
    const float* W2 = (const float*)d_in[5];
    const float* b2 = (const float*)d_in[6];
    const float* Wz = (const float*)d_in[7];
    const float* bz = (const float*)d_in[8];
    const float* Ws = (const float*)d_in[9];
    float* out = (float*)d_out;

    float* ws = (float*)d_ws;
    float* W1t = ws;                                   // 32768 f
    float* fz  = W1t + 64 * IN_;                       // N*128 f
    unsigned short* fx_hi  = (unsigned short*)(fz + (size_t)N_ * ZD);
    unsigned short* fx_lo  = fx_hi + (size_t)N_ * ZD;
    unsigned short* fz_hi  = fx_lo + (size_t)N_ * ZD;
    unsigned short* Wst_hi = fz_hi + (size_t)N_ * ZD;  // CC*128*128
    unsigned short* Wst_lo = Wst_hi + (size_t)CC * ZD * ZD;
    int* counts  = (int*)(Wst_lo + (size_t)CC * ZD * ZD);
    int* offsets = counts + CC;
    int* grouped = offsets + CC;

    k_pre   <<<512, 256, 0, stream>>>(c, W1, z, Wz, bz, Ws, W1t, fz, fz_hi,
                                      Wst_hi, Wst_lo, counts, offsets, grouped);
    k_hfx   <<<N_ / 32, 256, 0, stream>>>(x, W1t, b1, W2, b2, fx_hi, fx_lo);
    k_fused <<<CC * TI, 256, 0, stream>>>(fx_hi, fx_lo, Wst_hi, Wst_lo, fz,
                                          fz_hi, grouped, offsets, counts, out);
}

// Round 9
// 147.587 us; speedup vs baseline: 1.3834x; 1.0702x over previous
//
#include <hip/hip_runtime.h>
#include <math.h>

#define N_   8192
#define IN_  512
#define ZD   128
#define CC   64
#define HD   50
#define EPSF 1e-8f

typedef float vf4 __attribute__((ext_vector_type(4)));
typedef __attribute__((ext_vector_type(8))) short bfrag;   // 8 bf16 = 4 VGPR

#define MFMA16(a, b, c) __builtin_amdgcn_mfma_f32_16x16x32_bf16((a), (b), (c), 0, 0, 0)

__device__ __forceinline__ float softplus_f(float t) {
    return fmaxf(t, 0.f) + log1pf(expf(-fabsf(t)));   // stable softplus
}
__device__ __forceinline__ unsigned short bf16_rn(float x) {
    unsigned int u = __float_as_uint(x);
    return (unsigned short)((u + 0x7fff + ((u >> 16) & 1)) >> 16);
}
__device__ __forceinline__ float bf16_f(unsigned short h) {
    return __uint_as_float(((unsigned int)h) << 16);
}
__device__ __forceinline__ void split8(const float* v, bfrag& hi, bfrag& lo) {
    #pragma unroll
    for (int e = 0; e < 8; ++e) {
        unsigned short h = bf16_rn(v[e]);
        ((short*)&hi)[e] = (short)h;
        ((short*)&lo)[e] = (short)bf16_rn(v[e] - bf16_f(h));
    }
}

// ============================================================================
// k_pre: fused preprocessing.
//   blocks 0..63    : per-category grouping
//   blocks 64..79   : W1^T bf16 hi/lo packed in MFMA B-frag order (4 k-chunks)
//   blocks 80..83   : W2^T bf16 hi/lo packed in MFMA B-frag order
//   blocks 84..339  : fz = z @ Wz + bz  fp32  + fz_hi bf16 epilogue
//   blocks 340..403 : Ws[cat] -> Wst_hi/lo [e][d] bf16 (transpose + split)
// Packed frag layout (per 32-k step): frag f, lane l hold 8 consecutive bf16
// at uint4 index f*64+l — so LDS staging is a straight coalesced copy and
// B-frag ds_read_b128s are conflict-free.
// ============================================================================
__global__ __launch_bounds__(256) void k_pre(const int* __restrict__ c,
                                             const float* __restrict__ W1,
                                             const float* __restrict__ z,
                                             const float* __restrict__ Wz,
                                             const float* __restrict__ bz,
                                             const float* __restrict__ W2,
                                             const float* __restrict__ Ws,
                                             uint4* __restrict__ W1p,
                                             uint4* __restrict__ W2p,
                                             float* __restrict__ fz,
                                             unsigned short* __restrict__ fz_hi,
                                             unsigned short* __restrict__ Wst_hi,
                                             unsigned short* __restrict__ Wst_lo,
                                             int* __restrict__ counts,
                                             int* __restrict__ offsets,
                                             int* __restrict__ grouped) {
    __shared__ float smem[64 * 129];             // 33 KB union
    int tid = threadIdx.x;
    int b   = blockIdx.x;
    if (b < CC) {
        __shared__ int hist[CC];
        __shared__ int cursor;
        __shared__ int off_s;
        if (tid < CC) hist[tid] = 0;
        if (tid == 0) cursor = 0;
        __syncthreads();
        for (int i = tid; i < N_; i += 256) atomicAdd(&hist[c[i]], 1);
        __syncthreads();
        if (tid == 0) {
            int off = 0;
            for (int q = 0; q < b; ++q) off += hist[q];
            off_s = off;
            counts[b]  = hist[b];
            offsets[b] = off;
        }
        __syncthreads();
        int off = off_s;
        for (int i = tid; i < N_; i += 256) {
            if (c[i] == b) {
                int p = atomicAdd(&cursor, 1);
                grouped[off + p] = i;
            }
        }
    } else if (b < 80) {
        // ---- W1^T packed frags: unit = (kc, f, lane), 4096 units ----
        int unit = (b - 64) * 256 + tid;
        int lane = unit & 63, f = (unit >> 6) & 15, kc = unit >> 10;
        int nt = f >> 2, ks = f & 3;
        int n = nt * 16 + (lane & 15);           // h-col (0..63, pad >=50)
        int kbase = kc * 128 + ks * 32 + (lane >> 4) * 8;
        unsigned short hi8[8], lo8[8];
        #pragma unroll
        for (int j = 0; j < 8; ++j) {
            int k = kbase + j;
            float v = (n < HD) ? W1[k * HD + n] : 0.f;
            unsigned short h = bf16_rn(v);
            hi8[j] = h;
            lo8[j] = bf16_rn(v - bf16_f(h));
        }
        W1p[kc * 2048 + f * 64 + lane]        = *(uint4*)hi8;
        W1p[kc * 2048 + 1024 + f * 64 + lane] = *(uint4*)lo8;
    } else if (b < 84) {
        // ---- W2^T packed frags: unit = (f, lane), 1024 units ----
        int unit = (b - 80) * 256 + tid;
        int lane = unit & 63, f = unit >> 6;
        int nt = f >> 1, ks = f & 1;
        int n = nt * 16 + (lane & 15);           // fx-col (0..127)
        int kbase = ks * 32 + (lane >> 4) * 8;
        unsigned short hi8[8], lo8[8];
        #pragma unroll
        for (int j = 0; j < 8; ++j) {
            int k = kbase + j;
            float v = (k < HD) ? W2[k * ZD + n] : 0.f;
            unsigned short h = bf16_rn(v);
            hi8[j] = h;
            lo8[j] = bf16_rn(v - bf16_f(h));
        }
        W2p[f * 64 + lane]        = *(uint4*)hi8;
        W2p[1024 + f * 64 + lane] = *(uint4*)lo8;
    } else if (b < 340) {
        float* sz = smem;                        // 32*128 floats
        int row0 = (b - 84) * 32;
        vf4* s4 = (vf4*)sz;
        const vf4* z4 = (const vf4*)(z + (size_t)row0 * ZD);
        #pragma unroll
        for (int f = 0; f < 4; ++f) s4[tid + f * 256] = z4[tid + f * 256];
        __syncthreads();
        int cp = tid & 31, rg = tid >> 5;
        const vf4* Wz4 = (const vf4*)Wz;
        vf4 bb = ((const vf4*)bz)[cp];
        vf4 acc[4];
        #pragma unroll
        for (int r = 0; r < 4; ++r) acc[r] = bb;
        #pragma unroll 1
        for (int d4 = 0; d4 < 32; ++d4) {
            vf4 w0 = Wz4[(4 * d4 + 0) * 32 + cp];
            vf4 w1 = Wz4[(4 * d4 + 1) * 32 + cp];
            vf4 w2 = Wz4[(4 * d4 + 2) * 32 + cp];
            vf4 w3 = Wz4[(4 * d4 + 3) * 32 + cp];
            #pragma unroll
            for (int r = 0; r < 4; ++r) {
                vf4 a = s4[(rg * 4 + r) * 32 + d4];
                acc[r] += a[0] * w0;
                acc[r] += a[1] * w1;
                acc[r] += a[2] * w2;
                acc[r] += a[3] * w3;
            }
        }
        vf4* fz4 = (vf4*)fz;
        #pragma unroll
        for (int r = 0; r < 4; ++r) {
            int n = row0 + rg * 4 + r;
            fz4[(size_t)n * 32 + cp] = acc[r];
            ushort4 h;
            h.x = bf16_rn(acc[r][0]); h.y = bf16_rn(acc[r][1]);
            h.z = bf16_rn(acc[r][2]); h.w = bf16_rn(acc[r][3]);
            *(ushort4*)(fz_hi + (size_t)n * ZD + cp * 4) = h;
        }
    } else {
        int cat = b - 340;
        const float* Wc = Ws + (size_t)cat * ZD * ZD;
        unsigned short* Whi = Wst_hi + (size_t)cat * ZD * ZD;
        unsigned short* Wlo = Wst_lo + (size_t)cat * ZD * ZD;
        #pragma unroll 1
        for (int half = 0; half < 2; ++half) {
            __syncthreads();
            const vf4* src = (const vf4*)(Wc + (size_t)half * 64 * ZD);
            #pragma unroll
            for (int f = 0; f < 8; ++f) {        // 2048 vf4 = 64 rows x 32
                int idx = tid + f * 256;
                int row = idx >> 5, q = idx & 31;
                vf4 v = src[idx];
                #pragma unroll
                for (int e = 0; e < 4; ++e) smem[row * 129 + q * 4 + e] = v[e];
            }
            __syncthreads();
            #pragma unroll 1
            for (int f = 0; f < 32; ++f) {       // 8192 = 128 e x 64 dd
                int idx = tid + f * 256;
                int e = idx >> 6, dd = idx & 63;
                float v = smem[dd * 129 + e];
                unsigned short h = bf16_rn(v);
                Whi[(size_t)e * ZD + half * 64 + dd] = h;
                Wlo[(size_t)e * ZD + half * 64 + dd] = bf16_rn(v - bf16_f(h));
            }
        }
    }
}

// ============================================================================
// k_hfx v3 (MFMA): 64 rows/block, 128 blocks, 4 waves x 16 rows.
// Phase A: h = relu(x@W1+b1), K=512 in 4 LDS-staged chunks, 3-pass hi/lo
//          bf16 MFMA (B-frags conflict-free from packed W1p). x read once,
//          per-lane float4 pairs, split hi/lo in-register.
// Phase B: fx = h@W2+b2 via LDS h-tile round-trip + 3-pass MFMA vs W2p.
// Replaces the fp32-VALU GEMM that was LDS-issue-bound (~6 ds_read_b128
// per 32 FMA); MFMA does 4 MAC/LDS-byte instead.
// ============================================================================
__global__ __launch_bounds__(256) void k_hfx(const float* __restrict__ x,
                                             const uint4* __restrict__ W1p,
                                             const uint4* __restrict__ W2p,
                                             const float* __restrict__ b1,
                                             const float* __restrict__ b2,
                                             unsigned short* __restrict__ fx_hi,
                                             unsigned short* __restrict__ fx_lo) {
    __shared__ uint4 sW2[2048];                  // 32 KB (hi 0..1023, lo 1024..)
    __shared__ uint4 sW1[2048];                  // 32 KB per k-chunk
    __shared__ float sh[64 * 68];                // 17.4 KB h-tile
    int tid = threadIdx.x;
    int lane = tid & 63, w = tid >> 6, m = lane & 15, quad = lane >> 4;
    int i0 = blockIdx.x * 64;

    #pragma unroll
    for (int f = 0; f < 8; ++f) sW2[tid + f * 256] = W2p[tid + f * 256];

    int row = i0 + w * 16 + m;
    const float4* xr = (const float4*)(x + (size_t)row * IN_);

    vf4 acc[4];
    #pragma unroll
    for (int nt = 0; nt < 4; ++nt) acc[nt] = (vf4){0.f, 0.f, 0.f, 0.f};

    #pragma unroll 1
    for (int kc = 0; kc < 4; ++kc) {
        __syncthreads();
        #pragma unroll
        for (int f = 0; f < 8; ++f)
            sW1[tid + f * 256] = W1p[kc * 2048 + tid + f * 256];
        __syncthreads();
        #pragma unroll 1
        for (int ks = 0; ks < 4; ++ks) {
            float4 xa = xr[kc * 32 + ks * 8 + quad * 2];
            float4 xb = xr[kc * 32 + ks * 8 + quad * 2 + 1];
            float xv[8] = {xa.x, xa.y, xa.z, xa.w, xb.x, xb.y, xb.z, xb.w};
            bfrag ah, al;
            split8(xv, ah, al);
            #pragma unroll
            for (int nt = 0; nt < 4; ++nt) {
                bfrag bh = *(const bfrag*)&sW1[(nt * 4 + ks) * 64 + lane];
                bfrag bl = *(const bfrag*)&sW1[1024 + (nt * 4 + ks) * 64 + lane];
                acc[nt] = MFMA16(ah, bh, acc[nt]);
                acc[nt] = MFMA16(ah, bl, acc[nt]);
                acc[nt] = MFMA16(al, bh, acc[nt]);
            }
        }
    }
    // bias + relu -> sh  (C layout: col = nt*16+m, row = w*16+quad*4+r)
    #pragma unroll
    for (int nt = 0; nt < 4; ++nt) {
        int col = nt * 16 + m;
        float bb = (col < HD) ? b1[col] : 0.f;
        #pragma unroll
        for (int r = 0; r < 4; ++r)
            sh[(w * 16 + quad * 4 + r) * 68 + col] = fmaxf(acc[nt][r] + bb, 0.f);
    }
    __syncthreads();

    // phase B A-frags: row = w*16+m, k = ks*32+quad*8..+8
    bfrag ah2[2], al2[2];
    #pragma unroll
    for (int ks = 0; ks < 2; ++ks) {
        const float4* shp = (const float4*)&sh[(w * 16 + m) * 68 + ks * 32 + quad * 8];
        float4 ha = shp[0], hb = shp[1];
        float hv[8] = {ha.x, ha.y, ha.z, ha.w, hb.x, hb.y, hb.z, hb.w};
        split8(hv, ah2[ks], al2[ks]);
    }
    #pragma unroll 1
    for (int nt = 0; nt < 8; ++nt) {
        vf4 a2 = {0.f, 0.f, 0.f, 0.f};
        #pragma unroll
        for (int ks = 0; ks < 2; ++ks) {
            bfrag bh = *(const bfrag*)&sW2[(nt * 2 + ks) * 64 + lane];
            bfrag bl = *(const bfrag*)&sW2[1024 + (nt * 2 + ks) * 64 + lane];
            a2 = MFMA16(ah2[ks], bh, a2);
            a2 = MFMA16(ah2[ks], bl, a2);
            a2 = MFMA16(al2[ks], bh, a2);
        }
        int col = nt * 16 + m;
        float bb2 = b2[col];
        #pragma unroll
        for (int r = 0; r < 4; ++r) {
            size_t rg = (size_t)(i0 + w * 16 + quad * 4 + r);
            float v = a2[r] + bb2;
            unsigned short hh = bf16_rn(v);
            fx_hi[rg * ZD + col] = hh;
            fx_lo[rg * ZD + col] = bf16_rn(v - bf16_f(hh));
        }
    }
}

// ============================================================================
// k_fused: unchanged from round 8 (proven). Per (cat, 64-row i-tile):
// phase U (3-pass MFMA, acc in regs) -> phase T (fp32 dot + shfl) ->
// phase S (u_hi via LDS, 1-pass MFMA vs fz_hi chunks) -> out.
// ============================================================================
#define TI 4
__global__ __launch_bounds__(256) void k_fused(const unsigned short* __restrict__ fx_hi,
                                               const unsigned short* __restrict__ fx_lo,
                                               const unsigned short* __restrict__ Wst_hi,
                                               const unsigned short* __restrict__ Wst_lo,
                                               const float* __restrict__ fz,
                                               const unsigned short* __restrict__ fz_hi,
                                               const int* __restrict__ grouped,
                                               const int* __restrict__ offsets,
                                               const int* __restrict__ counts,
                                               float* __restrict__ out) {
    __shared__ uint4 sWhi[128 * 17];             // 34.8 KB; reused as su
    __shared__ uint4 sWlo[128 * 17];             // 34.8 KB; reused as sB
    int tid = threadIdx.x;
    int cat = blockIdx.x >> 2;
    int t   = blockIdx.x & (TI - 1);
    int off = offsets[cat], cnt = counts[cat];
    int i0 = t * 64;
    if (i0 >= cnt) return;
    int mI = min(64, cnt - i0);

    int lane = tid & 63, wave = tid >> 6;
    int m = lane & 15, quad = lane >> 4;

    const uint4* gh = (const uint4*)(Wst_hi + (size_t)cat * ZD * ZD);
    const uint4* gl = (const uint4*)(Wst_lo + (size_t)cat * ZD * ZD);
    #pragma unroll
    for (int f = 0; f < 8; ++f) {
        int idx = tid + f * 256;
        int e = idx >> 4, q = idx & 15;
        sWhi[e * 17 + q] = gh[idx];
        sWlo[e * 17 + q] = gl[idx];
    }

    int irow = wave * 16 + m;
    int n_gA = grouped[off + i0 + min(irow, mI - 1)];
    const unsigned short* fhp = fx_hi + (size_t)n_gA * ZD + quad * 8;
    const unsigned short* flp = fx_lo + (size_t)n_gA * ZD + quad * 8;
    bfrag a_hi[4], a_lo[4];
    #pragma unroll
    for (int kb = 0; kb < 4; ++kb) {
        a_hi[kb] = *(const bfrag*)(fhp + kb * 32);
        a_lo[kb] = *(const bfrag*)(flp + kb * 32);
    }
    __syncthreads();

    vf4 uacc[8];
    #pragma unroll 1
    for (int et = 0; et < 8; ++et) {
        vf4 acc = {0.f, 0.f, 0.f, 0.f};
        #pragma unroll
        for (int kb = 0; kb < 4; ++kb) {
            bfrag bh = *(const bfrag*)&sWhi[(et * 16 + m) * 17 + kb * 4 + quad];
            bfrag bl = *(const bfrag*)&sWlo[(et * 16 + m) * 17 + kb * 4 + quad];
            acc = MFMA16(a_hi[kb], bh, acc);
            acc = MFMA16(a_hi[kb], bl, acc);
            acc = MFMA16(a_lo[kb], bh, acc);
        }
        uacc[et] = acc;
    }

    int nrow[4];
    float p[4] = {0.f, 0.f, 0.f, 0.f};
    #pragma unroll
    for (int r = 0; r < 4; ++r) {
        int ir = wave * 16 + quad * 4 + r;
        nrow[r] = (ir < mI) ? grouped[off + i0 + ir] : -1;
    }
    #pragma unroll 1
    for (int et = 0; et < 8; ++et) {
        #pragma unroll
        for (int r = 0; r < 4; ++r) {
            if (nrow[r] >= 0)
                p[r] += uacc[et][r] * fz[(size_t)nrow[r] * ZD + et * 16 + m];
        }
    }
    #pragma unroll
    for (int r = 0; r < 4; ++r) {
        float v = p[r];
        #pragma unroll
        for (int s = 8; s >= 1; s >>= 1) v += __shfl_xor(v, s, 64);
        p[r] = v;
    }
    float logT_r[4];
    #pragma unroll
    for (int r = 0; r < 4; ++r) logT_r[r] = logf(softplus_f(p[r]) + EPSF);

    __syncthreads();
    unsigned short* su = (unsigned short*)sWhi;  // [row][e], stride 136
    #pragma unroll
    for (int et = 0; et < 8; ++et) {
        #pragma unroll
        for (int r = 0; r < 4; ++r) {
            int rowq = wave * 16 + quad * 4 + r;
            su[rowq * 136 + et * 16 + m] = bf16_rn(uacc[et][r]);
        }
    }
    __syncthreads();

    bfrag na[4];
    #pragma unroll
    for (int kb = 0; kb < 4; ++kb)
        na[kb] = *(const bfrag*)&su[(wave * 16 + m) * 136 + kb * 32 + quad * 8];

    uint4* sB = (uint4*)sWlo;
    float negsum[4] = {0.f, 0.f, 0.f, 0.f};

    #pragma unroll 1
    for (int jb = 0; jb < cnt; jb += 64) {
        int mJ = min(64, cnt - jb);
        __syncthreads();
        #pragma unroll
        for (int f = 0; f < 4; ++f) {
            int idx = tid + f * 256;
            int jr = idx >> 4, q = idx & 15;
            uint4 v = {0u, 0u, 0u, 0u};
            if (jr < mJ) {
                int j_g = grouped[off + jb + jr];
                v = *(const uint4*)(fz_hi + (size_t)j_g * ZD + q * 8);
            }
            sB[jr * 17 + q] = v;
        }
        __syncthreads();
        #pragma unroll 1
        for (int jt = 0; jt < 4; ++jt) {
            vf4 acc = {0.f, 0.f, 0.f, 0.f};
            #pragma unroll
            for (int kb = 0; kb < 4; ++kb) {
                bfrag bb = *(const bfrag*)&sB[(jt * 16 + m) * 17 + kb * 4 + quad];
                acc = MFMA16(na[kb], bb, acc);
            }
            bool jok = (jt * 16 + m) < mJ;
            #pragma unroll
            for (int r = 0; r < 4; ++r)
                if (jok) negsum[r] += softplus_f(acc[r]);
        }
    }

    #pragma unroll
    for (int r = 0; r < 4; ++r) {
        float v = negsum[r];
        #pragma unroll
        for (int s = 8; s >= 1; s >>= 1) v += __shfl_xor(v, s, 64);
        negsum[r] = v;
    }
    if (m == 0) {
        #pragma unroll
        for (int r = 0; r < 4; ++r) {
            if (nrow[r] >= 0)
                out[nrow[r]] = logT_r[r] - logf(negsum[r] / (float)cnt + EPSF);
        }
    }
}

extern "C" void kernel_launch(void* const* d_in, const int* in_sizes, int n_in,
                              void* d_out, int out_size, void* d_ws, size_t ws_size,
                              hipStream_t stream) {
    const float* x  = (const float*)d_in[0];
    const int*   c  = (const int*)  d_in[1];
    const float* z  = (const float*)d_in[2];
    const float* W1 = (const float*)d_in[3];
    const float* b1 = (const float*)d_in[4];
    const float* W2 = (const float*)d_in[5];
    const float* b2 = (const float*)d_in[6];
    const float* Wz = (const float*)d_in[7];
    const float* bz = (const float*)d_in[8];
    const float* Ws = (const float*)d_in[9];
    float* out = (float*)d_out;

    uint4* W1p = (uint4*)d_ws;                         // 8192 uint4 (128 KB)
    uint4* W2p = W1p + 8192;                           // 2048 uint4 (32 KB)
    float* fz  = (float*)(W2p + 2048);                 // N*128 f
    unsigned short* fx_hi  = (unsigned short*)(fz + (size_t)N_ * ZD);
    unsigned short* fx_lo  = fx_hi + (size_t)N_ * ZD;
    unsigned short* fz_hi  = fx_lo + (size_t)N_ * ZD;
    unsigned short* Wst_hi = fz_hi + (size_t)N_ * ZD;  // CC*128*128
    unsigned short* Wst_lo = Wst_hi + (size_t)CC * ZD * ZD;
    int* counts  = (int*)(Wst_lo + (size_t)CC * ZD * ZD);
    int* offsets = counts + CC;
    int* grouped = offsets + CC;

    k_pre   <<<404, 256, 0, stream>>>(c, W1, z, Wz, bz, W2, Ws, W1p, W2p, fz,
                                      fz_hi, Wst_hi, Wst_lo, counts, offsets,
                                      grouped);
    k_hfx   <<<N_ / 64, 256, 0, stream>>>(x, W1p, W2p, b1, b2, fx_hi, fx_lo);
    k_fused <<<CC * TI, 256, 0, stream>>>(fx_hi, fx_lo, Wst_hi, Wst_lo, fz,
                                          fz_hi, grouped, offsets, counts, out);
}